// Round 2
// baseline (198.185 us; speedup 1.0000x reference)
//
#include <hip/hip_runtime.h>
#include <hip/hip_bf16.h>

#define N_USER     50000
#define N_ITEM     10000
#define NUM_NODES  60000
#define EMBED_DIM  64
#define N_EDGES    2000000

// alpha[0] = 1/(NUM_LAYERS+1) = 1/3
#define ALPHA0 (1.0f / 3.0f)

// ---------------------------------------------------------------------------
// Phase 1: build fused node table in fp32:  nodes[n][d] = x[n][d] * alpha0
// One thread per element; a full wave covers one 64-dim row (coalesced).
// ---------------------------------------------------------------------------
__global__ __launch_bounds__(256) void build_nodes(
    const float* __restrict__ user_emb,
    const float* __restrict__ item_emb,
    const float* __restrict__ tag_emb,
    const float* __restrict__ testid_emb,
    const float* __restrict__ bigcat_emb,
    const float* __restrict__ daydiff_emb,
    const int* __restrict__ item_tags,
    const int* __restrict__ item_testids,
    const int* __restrict__ item_bigcat,
    const int* __restrict__ user_daydiff,
    float* __restrict__ nodes)
{
    int idx = blockIdx.x * blockDim.x + threadIdx.x;
    if (idx >= NUM_NODES * EMBED_DIM) return;
    int node = idx >> 6;      // /EMBED_DIM
    int d    = idx & 63;
    float v;
    if (node < N_USER) {
        int dd = user_daydiff[node];
        v = (user_emb[idx] + daydiff_emb[dd * EMBED_DIM + d]) * (0.5f * ALPHA0);
    } else {
        int i = node - N_USER;
        v = (item_emb[i * EMBED_DIM + d]
           + tag_emb[item_tags[i] * EMBED_DIM + d]
           + testid_emb[item_testids[i] * EMBED_DIM + d]
           + bigcat_emb[item_bigcat[i] * EMBED_DIM + d]) * (0.25f * ALPHA0);
    }
    nodes[idx] = v;
}

// ---------------------------------------------------------------------------
// Phase 2: per-edge dot product. 8 lanes per edge: each lane loads 8 floats
// (2 x float4) of src and dst rows, partial dot, shfl_xor reduce within the
// 8-lane group, then wave-level transpose so lanes 0..7 store 8 consecutive
// fp32 results (one coalesced 32B store per wave).
// ---------------------------------------------------------------------------
__global__ __launch_bounds__(256) void edge_dot(
    const float* __restrict__ nodes,
    const int*   __restrict__ edge_index,
    float* __restrict__ out)
{
    int tid  = blockIdx.x * 256 + threadIdx.x;
    int e    = tid >> 3;            // edge handled by this 8-lane group
    int g    = threadIdx.x & 7;     // lane within group
    int lane = threadIdx.x & 63;    // lane within wave

    float sum = 0.0f;
    if (e < N_EDGES) {
        int src = edge_index[e];
        int dst = edge_index[N_EDGES + e];
        const float4* s = (const float4*)(nodes + (size_t)src * EMBED_DIM) + (g << 1);
        const float4* t = (const float4*)(nodes + (size_t)dst * EMBED_DIM) + (g << 1);
        float4 a0 = s[0], a1 = s[1];
        float4 b0 = t[0], b1 = t[1];
        sum = a0.x * b0.x + a0.y * b0.y + a0.z * b0.z + a0.w * b0.w
            + a1.x * b1.x + a1.y * b1.y + a1.z * b1.z + a1.w * b1.w;
    }
    // reduce within the 8-lane group (all 8 lanes end with the full sum)
    sum += __shfl_xor(sum, 1, 8);
    sum += __shfl_xor(sum, 2, 8);
    sum += __shfl_xor(sum, 4, 8);

    // wave transpose: lane l (l<8) grabs group l's result -> coalesced store
    float r = __shfl(sum, (lane & 7) << 3, 64);
    if (lane < 8) {
        int waveBase = ((blockIdx.x * 256 + (threadIdx.x & ~63)) >> 3); // first edge of wave
        int eo = waveBase + lane;
        if (eo < N_EDGES) out[eo] = r;
    }
}

// ---------------------------------------------------------------------------
// Fallback (only if ws is too small): fused recompute of node rows per edge.
// ---------------------------------------------------------------------------
__device__ __forceinline__ void node_vals8(
    int node, int d0,
    const float* __restrict__ user_emb,
    const float* __restrict__ item_emb,
    const float* __restrict__ tag_emb,
    const float* __restrict__ testid_emb,
    const float* __restrict__ bigcat_emb,
    const float* __restrict__ daydiff_emb,
    const int* __restrict__ item_tags,
    const int* __restrict__ item_testids,
    const int* __restrict__ item_bigcat,
    const int* __restrict__ user_daydiff,
    float* v)
{
    if (node < N_USER) {
        int dd = user_daydiff[node];
        const float4* a = (const float4*)(user_emb    + (size_t)node * EMBED_DIM + d0);
        const float4* b = (const float4*)(daydiff_emb + (size_t)dd   * EMBED_DIM + d0);
        float4 a0 = a[0], a1 = a[1], b0 = b[0], b1 = b[1];
        v[0] = (a0.x + b0.x) * (0.5f * ALPHA0);
        v[1] = (a0.y + b0.y) * (0.5f * ALPHA0);
        v[2] = (a0.z + b0.z) * (0.5f * ALPHA0);
        v[3] = (a0.w + b0.w) * (0.5f * ALPHA0);
        v[4] = (a1.x + b1.x) * (0.5f * ALPHA0);
        v[5] = (a1.y + b1.y) * (0.5f * ALPHA0);
        v[6] = (a1.z + b1.z) * (0.5f * ALPHA0);
        v[7] = (a1.w + b1.w) * (0.5f * ALPHA0);
    } else {
        int i = node - N_USER;
        const float4* a = (const float4*)(item_emb   + (size_t)i * EMBED_DIM + d0);
        const float4* b = (const float4*)(tag_emb    + (size_t)item_tags[i]    * EMBED_DIM + d0);
        const float4* c = (const float4*)(testid_emb + (size_t)item_testids[i] * EMBED_DIM + d0);
        const float4* d = (const float4*)(bigcat_emb + (size_t)item_bigcat[i]  * EMBED_DIM + d0);
        float4 a0 = a[0], a1 = a[1], b0 = b[0], b1 = b[1];
        float4 c0 = c[0], c1 = c[1], d0v = d[0], d1 = d[1];
        v[0] = (a0.x + b0.x + c0.x + d0v.x) * (0.25f * ALPHA0);
        v[1] = (a0.y + b0.y + c0.y + d0v.y) * (0.25f * ALPHA0);
        v[2] = (a0.z + b0.z + c0.z + d0v.z) * (0.25f * ALPHA0);
        v[3] = (a0.w + b0.w + c0.w + d0v.w) * (0.25f * ALPHA0);
        v[4] = (a1.x + b1.x + c1.x + d1.x) * (0.25f * ALPHA0);
        v[5] = (a1.y + b1.y + c1.y + d1.y) * (0.25f * ALPHA0);
        v[6] = (a1.z + b1.z + c1.z + d1.z) * (0.25f * ALPHA0);
        v[7] = (a1.w + b1.w + c1.w + d1.w) * (0.25f * ALPHA0);
    }
}

__global__ __launch_bounds__(256) void edge_dot_fused(
    const float* __restrict__ user_emb,
    const float* __restrict__ item_emb,
    const float* __restrict__ tag_emb,
    const float* __restrict__ testid_emb,
    const float* __restrict__ bigcat_emb,
    const float* __restrict__ daydiff_emb,
    const int* __restrict__ edge_index,
    const int* __restrict__ item_tags,
    const int* __restrict__ item_testids,
    const int* __restrict__ item_bigcat,
    const int* __restrict__ user_daydiff,
    float* __restrict__ out)
{
    int tid  = blockIdx.x * 256 + threadIdx.x;
    int e    = tid >> 3;
    int g    = threadIdx.x & 7;
    int lane = threadIdx.x & 63;

    float sum = 0.0f;
    if (e < N_EDGES) {
        int src = edge_index[e];
        int dst = edge_index[N_EDGES + e];
        float a[8], b[8];
        node_vals8(src, g << 3, user_emb, item_emb, tag_emb, testid_emb,
                   bigcat_emb, daydiff_emb, item_tags, item_testids,
                   item_bigcat, user_daydiff, a);
        node_vals8(dst, g << 3, user_emb, item_emb, tag_emb, testid_emb,
                   bigcat_emb, daydiff_emb, item_tags, item_testids,
                   item_bigcat, user_daydiff, b);
        #pragma unroll
        for (int k = 0; k < 8; ++k) sum += a[k] * b[k];
    }
    sum += __shfl_xor(sum, 1, 8);
    sum += __shfl_xor(sum, 2, 8);
    sum += __shfl_xor(sum, 4, 8);

    float r = __shfl(sum, (lane & 7) << 3, 64);
    if (lane < 8) {
        int waveBase = ((blockIdx.x * 256 + (threadIdx.x & ~63)) >> 3);
        int eo = waveBase + lane;
        if (eo < N_EDGES) out[eo] = r;
    }
}

// ---------------------------------------------------------------------------
extern "C" void kernel_launch(void* const* d_in, const int* in_sizes, int n_in,
                              void* d_out, int out_size, void* d_ws, size_t ws_size,
                              hipStream_t stream)
{
    const float* user_emb    = (const float*)d_in[0];
    const float* item_emb    = (const float*)d_in[1];
    const float* tag_emb     = (const float*)d_in[2];
    const float* testid_emb  = (const float*)d_in[3];
    const float* bigcat_emb  = (const float*)d_in[4];
    const float* daydiff_emb = (const float*)d_in[5];
    const int* edge_index   = (const int*)d_in[6];
    const int* item_tags    = (const int*)d_in[7];
    const int* item_testids = (const int*)d_in[8];
    const int* item_bigcat  = (const int*)d_in[9];
    const int* user_daydiff = (const int*)d_in[10];
    float* out = (float*)d_out;

    const size_t node_bytes = (size_t)NUM_NODES * EMBED_DIM * sizeof(float);
    const int edge_blocks = (N_EDGES * 8 + 255) / 256;   // 8 lanes per edge

    if (ws_size >= node_bytes) {
        float* nodes = (float*)d_ws;
        int total = NUM_NODES * EMBED_DIM;
        build_nodes<<<(total + 255) / 256, 256, 0, stream>>>(
            user_emb, item_emb, tag_emb, testid_emb, bigcat_emb, daydiff_emb,
            item_tags, item_testids, item_bigcat, user_daydiff, nodes);
        edge_dot<<<edge_blocks, 256, 0, stream>>>(nodes, edge_index, out);
    } else {
        edge_dot_fused<<<edge_blocks, 256, 0, stream>>>(
            user_emb, item_emb, tag_emb, testid_emb, bigcat_emb, daydiff_emb,
            edge_index, item_tags, item_testids, item_bigcat, user_daydiff, out);
    }
}

// Round 3
// 147.940 us; speedup vs baseline: 1.3396x; 1.3396x over previous
//
#include <hip/hip_runtime.h>
#include <hip/hip_bf16.h>

#define N_USER     50000
#define N_ITEM     10000
#define NUM_NODES  60000
#define EMBED_DIM  64
#define N_EDGES    2000000

// alpha[0] = 1/(NUM_LAYERS+1) = 1/3
#define ALPHA0 (1.0f / 3.0f)

// round-to-nearest-even fp32 -> bf16 (as uint16 in low bits)
__device__ __forceinline__ unsigned f2bf(float x) {
    unsigned u = __float_as_uint(x);
    return (u + 0x7fffu + ((u >> 16) & 1u)) >> 16;
}

// ---------------------------------------------------------------------------
// Phase 1: build fused node table in packed bf16 (2 dims per u32):
//   nodes[n][d] = x[n][d] * alpha0,  row = 32 u32 = 128 B
// One thread per u32 (2 dims); 32 threads cover one row (coalesced).
// ---------------------------------------------------------------------------
__global__ __launch_bounds__(256) void build_nodes_bf16(
    const float* __restrict__ user_emb,
    const float* __restrict__ item_emb,
    const float* __restrict__ tag_emb,
    const float* __restrict__ testid_emb,
    const float* __restrict__ bigcat_emb,
    const float* __restrict__ daydiff_emb,
    const int* __restrict__ item_tags,
    const int* __restrict__ item_testids,
    const int* __restrict__ item_bigcat,
    const int* __restrict__ user_daydiff,
    unsigned* __restrict__ nodes)
{
    int idx = blockIdx.x * blockDim.x + threadIdx.x;       // u32 index
    if (idx >= NUM_NODES * (EMBED_DIM / 2)) return;
    int node = idx >> 5;          // / 32 u32-per-row
    int d    = (idx & 31) << 1;   // starting dim (even)
    float v0, v1;
    if (node < N_USER) {
        int dd = user_daydiff[node];
        const float2 a = *(const float2*)(user_emb    + (size_t)node * EMBED_DIM + d);
        const float2 b = *(const float2*)(daydiff_emb + (size_t)dd   * EMBED_DIM + d);
        v0 = (a.x + b.x) * (0.5f * ALPHA0);
        v1 = (a.y + b.y) * (0.5f * ALPHA0);
    } else {
        int i = node - N_USER;
        const float2 a = *(const float2*)(item_emb   + (size_t)i * EMBED_DIM + d);
        const float2 b = *(const float2*)(tag_emb    + (size_t)item_tags[i]    * EMBED_DIM + d);
        const float2 c = *(const float2*)(testid_emb + (size_t)item_testids[i] * EMBED_DIM + d);
        const float2 e = *(const float2*)(bigcat_emb + (size_t)item_bigcat[i]  * EMBED_DIM + d);
        v0 = (a.x + b.x + c.x + e.x) * (0.25f * ALPHA0);
        v1 = (a.y + b.y + c.y + e.y) * (0.25f * ALPHA0);
    }
    // element at lower dim goes in low 16 bits
    nodes[idx] = f2bf(v0) | (f2bf(v1) << 16);
}

// ---------------------------------------------------------------------------
// Phase 2: per-edge dot product over the bf16 table. 8 lanes per edge: each
// lane loads one uint4 (8 bf16 values = 16 B) of src and dst rows (the 8
// lanes cover the full 128 B row, coalesced), partial dot in fp32, shfl_xor
// reduce within the 8-lane group, then wave transpose for coalesced stores.
// ---------------------------------------------------------------------------
__device__ __forceinline__ float dot2u(unsigned a, unsigned b) {
    // low half = lower dim, high half = upper dim
    float alo = __uint_as_float(a << 16);
    float ahi = __uint_as_float(a & 0xffff0000u);
    float blo = __uint_as_float(b << 16);
    float bhi = __uint_as_float(b & 0xffff0000u);
    return alo * blo + ahi * bhi;
}

__global__ __launch_bounds__(256) void edge_dot_bf16(
    const unsigned* __restrict__ nodes,   // packed bf16, 32 u32 per row
    const int*      __restrict__ edge_index,
    float*          __restrict__ out)
{
    int tid  = blockIdx.x * 256 + threadIdx.x;
    int e    = tid >> 3;            // edge handled by this 8-lane group
    int g    = threadIdx.x & 7;     // lane within group
    int lane = threadIdx.x & 63;    // lane within wave

    float sum = 0.0f;
    if (e < N_EDGES) {
        int src = edge_index[e];
        int dst = edge_index[N_EDGES + e];
        const uint4* s = (const uint4*)(nodes + (size_t)src * 32) + g;
        const uint4* t = (const uint4*)(nodes + (size_t)dst * 32) + g;
        uint4 a = *s;
        uint4 b = *t;
        sum = dot2u(a.x, b.x) + dot2u(a.y, b.y)
            + dot2u(a.z, b.z) + dot2u(a.w, b.w);
    }
    // reduce within the 8-lane group (all 8 lanes end with the full sum)
    sum += __shfl_xor(sum, 1, 8);
    sum += __shfl_xor(sum, 2, 8);
    sum += __shfl_xor(sum, 4, 8);

    // wave transpose: lane l (l<8) grabs group l's result -> coalesced store
    float r = __shfl(sum, (lane & 7) << 3, 64);
    if (lane < 8) {
        int waveBase = ((blockIdx.x * 256 + (threadIdx.x & ~63)) >> 3); // first edge of wave
        int eo = waveBase + lane;
        if (eo < N_EDGES) out[eo] = r;
    }
}

// ---------------------------------------------------------------------------
// Fallback (only if ws is too small): fused fp32 recompute per edge.
// ---------------------------------------------------------------------------
__device__ __forceinline__ void node_vals8(
    int node, int d0,
    const float* __restrict__ user_emb,
    const float* __restrict__ item_emb,
    const float* __restrict__ tag_emb,
    const float* __restrict__ testid_emb,
    const float* __restrict__ bigcat_emb,
    const float* __restrict__ daydiff_emb,
    const int* __restrict__ item_tags,
    const int* __restrict__ item_testids,
    const int* __restrict__ item_bigcat,
    const int* __restrict__ user_daydiff,
    float* v)
{
    if (node < N_USER) {
        int dd = user_daydiff[node];
        const float4* a = (const float4*)(user_emb    + (size_t)node * EMBED_DIM + d0);
        const float4* b = (const float4*)(daydiff_emb + (size_t)dd   * EMBED_DIM + d0);
        float4 a0 = a[0], a1 = a[1], b0 = b[0], b1 = b[1];
        v[0] = (a0.x + b0.x) * (0.5f * ALPHA0);
        v[1] = (a0.y + b0.y) * (0.5f * ALPHA0);
        v[2] = (a0.z + b0.z) * (0.5f * ALPHA0);
        v[3] = (a0.w + b0.w) * (0.5f * ALPHA0);
        v[4] = (a1.x + b1.x) * (0.5f * ALPHA0);
        v[5] = (a1.y + b1.y) * (0.5f * ALPHA0);
        v[6] = (a1.z + b1.z) * (0.5f * ALPHA0);
        v[7] = (a1.w + b1.w) * (0.5f * ALPHA0);
    } else {
        int i = node - N_USER;
        const float4* a = (const float4*)(item_emb   + (size_t)i * EMBED_DIM + d0);
        const float4* b = (const float4*)(tag_emb    + (size_t)item_tags[i]    * EMBED_DIM + d0);
        const float4* c = (const float4*)(testid_emb + (size_t)item_testids[i] * EMBED_DIM + d0);
        const float4* d = (const float4*)(bigcat_emb + (size_t)item_bigcat[i]  * EMBED_DIM + d0);
        float4 a0 = a[0], a1 = a[1], b0 = b[0], b1 = b[1];
        float4 c0 = c[0], c1 = c[1], d0v = d[0], d1 = d[1];
        v[0] = (a0.x + b0.x + c0.x + d0v.x) * (0.25f * ALPHA0);
        v[1] = (a0.y + b0.y + c0.y + d0v.y) * (0.25f * ALPHA0);
        v[2] = (a0.z + b0.z + c0.z + d0v.z) * (0.25f * ALPHA0);
        v[3] = (a0.w + b0.w + c0.w + d0v.w) * (0.25f * ALPHA0);
        v[4] = (a1.x + b1.x + c1.x + d1.x) * (0.25f * ALPHA0);
        v[5] = (a1.y + b1.y + c1.y + d1.y) * (0.25f * ALPHA0);
        v[6] = (a1.z + b1.z + c1.z + d1.z) * (0.25f * ALPHA0);
        v[7] = (a1.w + b1.w + c1.w + d1.w) * (0.25f * ALPHA0);
    }
}

__global__ __launch_bounds__(256) void edge_dot_fused(
    const float* __restrict__ user_emb,
    const float* __restrict__ item_emb,
    const float* __restrict__ tag_emb,
    const float* __restrict__ testid_emb,
    const float* __restrict__ bigcat_emb,
    const float* __restrict__ daydiff_emb,
    const int* __restrict__ edge_index,
    const int* __restrict__ item_tags,
    const int* __restrict__ item_testids,
    const int* __restrict__ item_bigcat,
    const int* __restrict__ user_daydiff,
    float* __restrict__ out)
{
    int tid  = blockIdx.x * 256 + threadIdx.x;
    int e    = tid >> 3;
    int g    = threadIdx.x & 7;
    int lane = threadIdx.x & 63;

    float sum = 0.0f;
    if (e < N_EDGES) {
        int src = edge_index[e];
        int dst = edge_index[N_EDGES + e];
        float a[8], b[8];
        node_vals8(src, g << 3, user_emb, item_emb, tag_emb, testid_emb,
                   bigcat_emb, daydiff_emb, item_tags, item_testids,
                   item_bigcat, user_daydiff, a);
        node_vals8(dst, g << 3, user_emb, item_emb, tag_emb, testid_emb,
                   bigcat_emb, daydiff_emb, item_tags, item_testids,
                   item_bigcat, user_daydiff, b);
        #pragma unroll
        for (int k = 0; k < 8; ++k) sum += a[k] * b[k];
    }
    sum += __shfl_xor(sum, 1, 8);
    sum += __shfl_xor(sum, 2, 8);
    sum += __shfl_xor(sum, 4, 8);

    float r = __shfl(sum, (lane & 7) << 3, 64);
    if (lane < 8) {
        int waveBase = ((blockIdx.x * 256 + (threadIdx.x & ~63)) >> 3);
        int eo = waveBase + lane;
        if (eo < N_EDGES) out[eo] = r;
    }
}

// ---------------------------------------------------------------------------
extern "C" void kernel_launch(void* const* d_in, const int* in_sizes, int n_in,
                              void* d_out, int out_size, void* d_ws, size_t ws_size,
                              hipStream_t stream)
{
    const float* user_emb    = (const float*)d_in[0];
    const float* item_emb    = (const float*)d_in[1];
    const float* tag_emb     = (const float*)d_in[2];
    const float* testid_emb  = (const float*)d_in[3];
    const float* bigcat_emb  = (const float*)d_in[4];
    const float* daydiff_emb = (const float*)d_in[5];
    const int* edge_index   = (const int*)d_in[6];
    const int* item_tags    = (const int*)d_in[7];
    const int* item_testids = (const int*)d_in[8];
    const int* item_bigcat  = (const int*)d_in[9];
    const int* user_daydiff = (const int*)d_in[10];
    float* out = (float*)d_out;

    const size_t node_bytes = (size_t)NUM_NODES * (EMBED_DIM / 2) * sizeof(unsigned); // 7.68 MB
    const int edge_blocks = (N_EDGES * 8 + 255) / 256;   // 8 lanes per edge

    if (ws_size >= node_bytes) {
        unsigned* nodes = (unsigned*)d_ws;
        int total = NUM_NODES * (EMBED_DIM / 2);
        build_nodes_bf16<<<(total + 255) / 256, 256, 0, stream>>>(
            user_emb, item_emb, tag_emb, testid_emb, bigcat_emb, daydiff_emb,
            item_tags, item_testids, item_bigcat, user_daydiff, nodes);
        edge_dot_bf16<<<edge_blocks, 256, 0, stream>>>(nodes, edge_index, out);
    } else {
        edge_dot_fused<<<edge_blocks, 256, 0, stream>>>(
            user_emb, item_emb, tag_emb, testid_emb, bigcat_emb, daydiff_emb,
            edge_index, item_tags, item_testids, item_bigcat, user_daydiff, out);
    }
}

// Round 4
// 131.977 us; speedup vs baseline: 1.5017x; 1.1209x over previous
//
#include <hip/hip_runtime.h>
#include <hip/hip_bf16.h>

#define N_USER     50000
#define N_ITEM     10000
#define NUM_NODES  60000
#define EMBED_DIM  64
#define N_EDGES    2000000

// alpha[0] = 1/(NUM_LAYERS+1) = 1/3
#define ALPHA0 (1.0f / 3.0f)

// Edges per 8-lane group (unroll factor). N_EDGES % (EPG*8 groups/wave) == 0.
#define EPG 4

// round-to-nearest-even fp32 -> bf16 (as uint16 in low bits)
__device__ __forceinline__ unsigned f2bf(float x) {
    unsigned u = __float_as_uint(x);
    return (u + 0x7fffu + ((u >> 16) & 1u)) >> 16;
}

// ---------------------------------------------------------------------------
// Phase 1: build fused node table in packed bf16 (2 dims per u32):
//   nodes[n][d] = x[n][d] * alpha0,  row = 32 u32 = 128 B
// ---------------------------------------------------------------------------
__global__ __launch_bounds__(256) void build_nodes_bf16(
    const float* __restrict__ user_emb,
    const float* __restrict__ item_emb,
    const float* __restrict__ tag_emb,
    const float* __restrict__ testid_emb,
    const float* __restrict__ bigcat_emb,
    const float* __restrict__ daydiff_emb,
    const int* __restrict__ item_tags,
    const int* __restrict__ item_testids,
    const int* __restrict__ item_bigcat,
    const int* __restrict__ user_daydiff,
    unsigned* __restrict__ nodes)
{
    int idx = blockIdx.x * blockDim.x + threadIdx.x;       // u32 index
    if (idx >= NUM_NODES * (EMBED_DIM / 2)) return;
    int node = idx >> 5;          // / 32 u32-per-row
    int d    = (idx & 31) << 1;   // starting dim (even)
    float v0, v1;
    if (node < N_USER) {
        int dd = user_daydiff[node];
        const float2 a = *(const float2*)(user_emb    + (size_t)node * EMBED_DIM + d);
        const float2 b = *(const float2*)(daydiff_emb + (size_t)dd   * EMBED_DIM + d);
        v0 = (a.x + b.x) * (0.5f * ALPHA0);
        v1 = (a.y + b.y) * (0.5f * ALPHA0);
    } else {
        int i = node - N_USER;
        const float2 a = *(const float2*)(item_emb   + (size_t)i * EMBED_DIM + d);
        const float2 b = *(const float2*)(tag_emb    + (size_t)item_tags[i]    * EMBED_DIM + d);
        const float2 c = *(const float2*)(testid_emb + (size_t)item_testids[i] * EMBED_DIM + d);
        const float2 e = *(const float2*)(bigcat_emb + (size_t)item_bigcat[i]  * EMBED_DIM + d);
        v0 = (a.x + b.x + c.x + e.x) * (0.25f * ALPHA0);
        v1 = (a.y + b.y + c.y + e.y) * (0.25f * ALPHA0);
    }
    nodes[idx] = f2bf(v0) | (f2bf(v1) << 16);
}

// ---------------------------------------------------------------------------
// Phase 2: per-edge dot over the bf16 table. 8 lanes per edge, EPG=4 edges
// per group: each lane issues 8 independent 16B gathers (4 src + 4 dst rows)
// before any use -> high MLP to hide L2/HBM gather latency. shfl_xor reduce
// within the 8-lane group, wave transpose so lanes 0..31 store 32 consecutive
// fp32 results (one coalesced 128B nontemporal store per wave).
// edge_index reads and out writes are nontemporal: streamed once, keep the
// node table resident in L2 instead.
// ---------------------------------------------------------------------------
__device__ __forceinline__ void dot2acc(unsigned a, unsigned b, float2& acc) {
    float alo = __uint_as_float(a << 16);
    float ahi = __uint_as_float(a & 0xffff0000u);
    float blo = __uint_as_float(b << 16);
    float bhi = __uint_as_float(b & 0xffff0000u);
    acc.x = fmaf(alo, blo, acc.x);
    acc.y = fmaf(ahi, bhi, acc.y);
}

__global__ __launch_bounds__(256) void edge_dot_bf16(
    const unsigned* __restrict__ nodes,   // packed bf16, 32 u32 per row
    const int*      __restrict__ edge_index,
    float*          __restrict__ out)
{
    const int g    = threadIdx.x & 7;     // lane within 8-lane group
    const int lane = threadIdx.x & 63;    // lane within wave
    const int grp  = (blockIdx.x * 256 + threadIdx.x) >> 3;   // global group id
    const int e0   = grp * EPG;           // first of EPG consecutive edges

    // 4 src + 4 dst indices via four 8B nontemporal loads (e0 is even)
    const unsigned long long* src64 = (const unsigned long long*)edge_index;
    const unsigned long long* dst64 = (const unsigned long long*)(edge_index + N_EDGES);
    unsigned long long sA = __builtin_nontemporal_load(src64 + (e0 >> 1));
    unsigned long long sB = __builtin_nontemporal_load(src64 + (e0 >> 1) + 1);
    unsigned long long dA = __builtin_nontemporal_load(dst64 + (e0 >> 1));
    unsigned long long dB = __builtin_nontemporal_load(dst64 + (e0 >> 1) + 1);
    int s[EPG] = { (int)sA, (int)(sA >> 32), (int)sB, (int)(sB >> 32) };
    int d[EPG] = { (int)dA, (int)(dA >> 32), (int)dB, (int)(dB >> 32) };

    // issue all 8 gathers before any use
    uint4 av[EPG], bv[EPG];
    #pragma unroll
    for (int j = 0; j < EPG; ++j) {
        av[j] = *((const uint4*)(nodes + (size_t)s[j] * 32) + g);
        bv[j] = *((const uint4*)(nodes + (size_t)d[j] * 32) + g);
    }

    float sum[EPG];
    #pragma unroll
    for (int j = 0; j < EPG; ++j) {
        float2 acc = make_float2(0.0f, 0.0f);
        dot2acc(av[j].x, bv[j].x, acc);
        dot2acc(av[j].y, bv[j].y, acc);
        dot2acc(av[j].z, bv[j].z, acc);
        dot2acc(av[j].w, bv[j].w, acc);
        sum[j] = acc.x + acc.y;
    }

    // reduce within each 8-lane group (4 independent chains, pipelined)
    #pragma unroll
    for (int j = 0; j < EPG; ++j) {
        sum[j] += __shfl_xor(sum[j], 1, 8);
        sum[j] += __shfl_xor(sum[j], 2, 8);
        sum[j] += __shfl_xor(sum[j], 4, 8);
    }

    // wave transpose: wave covers 32 consecutive edges; lane l<32 stores
    // edge firstEdge+l, produced by group (l>>2) at wave-lane (l>>2)*8,
    // unroll slot j = l&3.
    int firstEdge = ((blockIdx.x * 256 + (threadIdx.x & ~63)) >> 3) * EPG;
    int srcLane = (lane >> 2) << 3;
    float r0 = __shfl(sum[0], srcLane, 64);
    float r1 = __shfl(sum[1], srcLane, 64);
    float r2 = __shfl(sum[2], srcLane, 64);
    float r3 = __shfl(sum[3], srcLane, 64);
    if (lane < 32) {
        int j = lane & 3;
        float r = (j == 0) ? r0 : (j == 1) ? r1 : (j == 2) ? r2 : r3;
        __builtin_nontemporal_store(r, out + firstEdge + lane);
    }
}

// ---------------------------------------------------------------------------
// Fallback (only if ws is too small): fused fp32 recompute per edge.
// ---------------------------------------------------------------------------
__device__ __forceinline__ void node_vals8(
    int node, int d0,
    const float* __restrict__ user_emb,
    const float* __restrict__ item_emb,
    const float* __restrict__ tag_emb,
    const float* __restrict__ testid_emb,
    const float* __restrict__ bigcat_emb,
    const float* __restrict__ daydiff_emb,
    const int* __restrict__ item_tags,
    const int* __restrict__ item_testids,
    const int* __restrict__ item_bigcat,
    const int* __restrict__ user_daydiff,
    float* v)
{
    if (node < N_USER) {
        int dd = user_daydiff[node];
        const float4* a = (const float4*)(user_emb    + (size_t)node * EMBED_DIM + d0);
        const float4* b = (const float4*)(daydiff_emb + (size_t)dd   * EMBED_DIM + d0);
        float4 a0 = a[0], a1 = a[1], b0 = b[0], b1 = b[1];
        v[0] = (a0.x + b0.x) * (0.5f * ALPHA0);
        v[1] = (a0.y + b0.y) * (0.5f * ALPHA0);
        v[2] = (a0.z + b0.z) * (0.5f * ALPHA0);
        v[3] = (a0.w + b0.w) * (0.5f * ALPHA0);
        v[4] = (a1.x + b1.x) * (0.5f * ALPHA0);
        v[5] = (a1.y + b1.y) * (0.5f * ALPHA0);
        v[6] = (a1.z + b1.z) * (0.5f * ALPHA0);
        v[7] = (a1.w + b1.w) * (0.5f * ALPHA0);
    } else {
        int i = node - N_USER;
        const float4* a = (const float4*)(item_emb   + (size_t)i * EMBED_DIM + d0);
        const float4* b = (const float4*)(tag_emb    + (size_t)item_tags[i]    * EMBED_DIM + d0);
        const float4* c = (const float4*)(testid_emb + (size_t)item_testids[i] * EMBED_DIM + d0);
        const float4* d = (const float4*)(bigcat_emb + (size_t)item_bigcat[i]  * EMBED_DIM + d0);
        float4 a0 = a[0], a1 = a[1], b0 = b[0], b1 = b[1];
        float4 c0 = c[0], c1 = c[1], d0v = d[0], d1 = d[1];
        v[0] = (a0.x + b0.x + c0.x + d0v.x) * (0.25f * ALPHA0);
        v[1] = (a0.y + b0.y + c0.y + d0v.y) * (0.25f * ALPHA0);
        v[2] = (a0.z + b0.z + c0.z + d0v.z) * (0.25f * ALPHA0);
        v[3] = (a0.w + b0.w + c0.w + d0v.w) * (0.25f * ALPHA0);
        v[4] = (a1.x + b1.x + c1.x + d1.x) * (0.25f * ALPHA0);
        v[5] = (a1.y + b1.y + c1.y + d1.y) * (0.25f * ALPHA0);
        v[6] = (a1.z + b1.z + c1.z + d1.z) * (0.25f * ALPHA0);
        v[7] = (a1.w + b1.w + c1.w + d1.w) * (0.25f * ALPHA0);
    }
}

__global__ __launch_bounds__(256) void edge_dot_fused(
    const float* __restrict__ user_emb,
    const float* __restrict__ item_emb,
    const float* __restrict__ tag_emb,
    const float* __restrict__ testid_emb,
    const float* __restrict__ bigcat_emb,
    const float* __restrict__ daydiff_emb,
    const int* __restrict__ edge_index,
    const int* __restrict__ item_tags,
    const int* __restrict__ item_testids,
    const int* __restrict__ item_bigcat,
    const int* __restrict__ user_daydiff,
    float* __restrict__ out)
{
    int tid  = blockIdx.x * 256 + threadIdx.x;
    int e    = tid >> 3;
    int g    = threadIdx.x & 7;
    int lane = threadIdx.x & 63;

    float sum = 0.0f;
    if (e < N_EDGES) {
        int src = edge_index[e];
        int dst = edge_index[N_EDGES + e];
        float a[8], b[8];
        node_vals8(src, g << 3, user_emb, item_emb, tag_emb, testid_emb,
                   bigcat_emb, daydiff_emb, item_tags, item_testids,
                   item_bigcat, user_daydiff, a);
        node_vals8(dst, g << 3, user_emb, item_emb, tag_emb, testid_emb,
                   bigcat_emb, daydiff_emb, item_tags, item_testids,
                   item_bigcat, user_daydiff, b);
        #pragma unroll
        for (int k = 0; k < 8; ++k) sum += a[k] * b[k];
    }
    sum += __shfl_xor(sum, 1, 8);
    sum += __shfl_xor(sum, 2, 8);
    sum += __shfl_xor(sum, 4, 8);

    float r = __shfl(sum, (lane & 7) << 3, 64);
    if (lane < 8) {
        int waveBase = ((blockIdx.x * 256 + (threadIdx.x & ~63)) >> 3);
        int eo = waveBase + lane;
        if (eo < N_EDGES) out[eo] = r;
    }
}

// ---------------------------------------------------------------------------
extern "C" void kernel_launch(void* const* d_in, const int* in_sizes, int n_in,
                              void* d_out, int out_size, void* d_ws, size_t ws_size,
                              hipStream_t stream)
{
    const float* user_emb    = (const float*)d_in[0];
    const float* item_emb    = (const float*)d_in[1];
    const float* tag_emb     = (const float*)d_in[2];
    const float* testid_emb  = (const float*)d_in[3];
    const float* bigcat_emb  = (const float*)d_in[4];
    const float* daydiff_emb = (const float*)d_in[5];
    const int* edge_index   = (const int*)d_in[6];
    const int* item_tags    = (const int*)d_in[7];
    const int* item_testids = (const int*)d_in[8];
    const int* item_bigcat  = (const int*)d_in[9];
    const int* user_daydiff = (const int*)d_in[10];
    float* out = (float*)d_out;

    const size_t node_bytes = (size_t)NUM_NODES * (EMBED_DIM / 2) * sizeof(unsigned); // 7.68 MB

    if (ws_size >= node_bytes) {
        unsigned* nodes = (unsigned*)d_ws;
        int total = NUM_NODES * (EMBED_DIM / 2);
        build_nodes_bf16<<<(total + 255) / 256, 256, 0, stream>>>(
            user_emb, item_emb, tag_emb, testid_emb, bigcat_emb, daydiff_emb,
            item_tags, item_testids, item_bigcat, user_daydiff, nodes);
        // EPG edges per 8-lane group: N_EDGES*8/EPG threads, exact division
        const int edge_blocks = (N_EDGES / EPG * 8) / 256;  // 15625
        edge_dot_bf16<<<edge_blocks, 256, 0, stream>>>(nodes, edge_index, out);
    } else {
        const int edge_blocks = (N_EDGES * 8 + 255) / 256;
        edge_dot_fused<<<edge_blocks, 256, 0, stream>>>(
            user_emb, item_emb, tag_emb, testid_emb, bigcat_emb, daydiff_emb,
            edge_index, item_tags, item_testids, item_bigcat, user_daydiff, out);
    }
}

// Round 5
// 130.217 us; speedup vs baseline: 1.5220x; 1.0135x over previous
//
#include <hip/hip_runtime.h>
#include <hip/hip_bf16.h>
#include <hip/hip_fp16.h>

#define N_USER     50000
#define N_ITEM     10000
#define NUM_NODES  60000
#define EMBED_DIM  64
#define N_EDGES    2000000

// alpha[0] = 1/(NUM_LAYERS+1) = 1/3
#define ALPHA0 (1.0f / 3.0f)

// Edges per 8-lane group (unroll factor). N_EDGES % (EPG * 8 groups/wave) == 0.
#define EPG 4

#if defined(__has_builtin)
#  if __has_builtin(__builtin_amdgcn_fdot2)
#    define HAVE_FDOT2 1
#  endif
#endif

typedef _Float16 h2_t __attribute__((ext_vector_type(2)));
union U32H2 { unsigned u; h2_t h; };

// ---------------------------------------------------------------------------
// Phase 1: build fused node table in packed fp16 (2 dims per u32):
//   nodes[n][d] = x[n][d] * alpha0,  row = 32 u32 = 128 B.
// One thread per 4 dims (uint2 store); 16 threads cover one row (coalesced
// float4 loads, 8B stores).
// ---------------------------------------------------------------------------
__global__ __launch_bounds__(256) void build_nodes_f16(
    const float* __restrict__ user_emb,
    const float* __restrict__ item_emb,
    const float* __restrict__ tag_emb,
    const float* __restrict__ testid_emb,
    const float* __restrict__ bigcat_emb,
    const float* __restrict__ daydiff_emb,
    const int* __restrict__ item_tags,
    const int* __restrict__ item_testids,
    const int* __restrict__ item_bigcat,
    const int* __restrict__ user_daydiff,
    unsigned* __restrict__ nodes)
{
    int idx = blockIdx.x * blockDim.x + threadIdx.x;   // uint2 (4-dim) index
    if (idx >= NUM_NODES * (EMBED_DIM / 4)) return;
    int node = idx >> 4;          // / 16 uint2-per-row
    int d    = (idx & 15) << 2;   // starting dim (multiple of 4 -> 16B aligned)
    float v0, v1, v2, v3;
    if (node < N_USER) {
        int dd = user_daydiff[node];
        const float4 a = *(const float4*)(user_emb    + (size_t)node * EMBED_DIM + d);
        const float4 b = *(const float4*)(daydiff_emb + (size_t)dd   * EMBED_DIM + d);
        v0 = (a.x + b.x) * (0.5f * ALPHA0);
        v1 = (a.y + b.y) * (0.5f * ALPHA0);
        v2 = (a.z + b.z) * (0.5f * ALPHA0);
        v3 = (a.w + b.w) * (0.5f * ALPHA0);
    } else {
        int i = node - N_USER;
        const float4 a = *(const float4*)(item_emb   + (size_t)i * EMBED_DIM + d);
        const float4 b = *(const float4*)(tag_emb    + (size_t)item_tags[i]    * EMBED_DIM + d);
        const float4 c = *(const float4*)(testid_emb + (size_t)item_testids[i] * EMBED_DIM + d);
        const float4 e = *(const float4*)(bigcat_emb + (size_t)item_bigcat[i]  * EMBED_DIM + d);
        v0 = (a.x + b.x + c.x + e.x) * (0.25f * ALPHA0);
        v1 = (a.y + b.y + c.y + e.y) * (0.25f * ALPHA0);
        v2 = (a.z + b.z + c.z + e.z) * (0.25f * ALPHA0);
        v3 = (a.w + b.w + c.w + e.w) * (0.25f * ALPHA0);
    }
    U32H2 p0, p1;
    p0.h = h2_t{(_Float16)v0, (_Float16)v1};
    p1.h = h2_t{(_Float16)v2, (_Float16)v3};
    ((uint2*)nodes)[idx] = make_uint2(p0.u, p1.u);
}

// ---------------------------------------------------------------------------
// Phase 2: per-edge dot over the fp16 table. 8 lanes per edge, EPG=4 edges
// per group: each lane issues 8 independent 16B gathers (4 src + 4 dst rows)
// before any use -> high MLP hides L2/HBM gather latency. Dot via
// v_dot2_f32_f16 (1 instr per packed pair, fp32 accumulate). shfl_xor reduce
// within the 8-lane group, wave transpose for one coalesced 128B store.
// edge_index reads / out writes nontemporal: streamed once, keep the node
// table resident in L2.
// ---------------------------------------------------------------------------
__device__ __forceinline__ float dotp(unsigned a, unsigned b, float acc) {
#ifdef HAVE_FDOT2
    U32H2 ua, ub; ua.u = a; ub.u = b;
    return __builtin_amdgcn_fdot2(ua.h, ub.h, acc, false);
#else
    const __half2 ha = *(const __half2*)&a;
    const __half2 hb = *(const __half2*)&b;
    float2 fa = __half22float2(ha);
    float2 fb = __half22float2(hb);
    return fmaf(fa.x, fb.x, fmaf(fa.y, fb.y, acc));
#endif
}

__global__ __launch_bounds__(256) void edge_dot_f16(
    const unsigned* __restrict__ nodes,   // packed fp16, 32 u32 per row
    const int*      __restrict__ edge_index,
    float*          __restrict__ out)
{
    const int g    = threadIdx.x & 7;     // lane within 8-lane group
    const int lane = threadIdx.x & 63;    // lane within wave
    const int grp  = (blockIdx.x * 256 + threadIdx.x) >> 3;   // global group id
    const int e0   = grp * EPG;           // first of EPG consecutive edges

    // 4 src + 4 dst indices via four 8B nontemporal loads (e0 is even)
    const unsigned long long* src64 = (const unsigned long long*)edge_index;
    const unsigned long long* dst64 = (const unsigned long long*)(edge_index + N_EDGES);
    unsigned long long sA = __builtin_nontemporal_load(src64 + (e0 >> 1));
    unsigned long long sB = __builtin_nontemporal_load(src64 + (e0 >> 1) + 1);
    unsigned long long dA = __builtin_nontemporal_load(dst64 + (e0 >> 1));
    unsigned long long dB = __builtin_nontemporal_load(dst64 + (e0 >> 1) + 1);
    int s[EPG] = { (int)sA, (int)(sA >> 32), (int)sB, (int)(sB >> 32) };
    int d[EPG] = { (int)dA, (int)(dA >> 32), (int)dB, (int)(dB >> 32) };

    // issue all 8 gathers before any use
    uint4 av[EPG], bv[EPG];
    #pragma unroll
    for (int j = 0; j < EPG; ++j) {
        av[j] = *((const uint4*)(nodes + (size_t)s[j] * 32) + g);
        bv[j] = *((const uint4*)(nodes + (size_t)d[j] * 32) + g);
    }

    float sum[EPG];
    #pragma unroll
    for (int j = 0; j < EPG; ++j) {
        float acc = 0.0f;
        acc = dotp(av[j].x, bv[j].x, acc);
        acc = dotp(av[j].y, bv[j].y, acc);
        acc = dotp(av[j].z, bv[j].z, acc);
        acc = dotp(av[j].w, bv[j].w, acc);
        sum[j] = acc;
    }

    // reduce within each 8-lane group (4 independent chains, pipelined)
    #pragma unroll
    for (int j = 0; j < EPG; ++j) {
        sum[j] += __shfl_xor(sum[j], 1, 8);
        sum[j] += __shfl_xor(sum[j], 2, 8);
        sum[j] += __shfl_xor(sum[j], 4, 8);
    }

    // wave transpose: wave covers 32 consecutive edges; lane l<32 stores
    // edge firstEdge+l, produced by group (l>>2) at wave-lane (l>>2)*8,
    // unroll slot j = l&3.
    int firstEdge = ((blockIdx.x * 256 + (threadIdx.x & ~63)) >> 3) * EPG;
    int srcLane = (lane >> 2) << 3;
    float r0 = __shfl(sum[0], srcLane, 64);
    float r1 = __shfl(sum[1], srcLane, 64);
    float r2 = __shfl(sum[2], srcLane, 64);
    float r3 = __shfl(sum[3], srcLane, 64);
    if (lane < 32) {
        int j = lane & 3;
        float r = (j == 0) ? r0 : (j == 1) ? r1 : (j == 2) ? r2 : r3;
        __builtin_nontemporal_store(r, out + firstEdge + lane);
    }
}

// ---------------------------------------------------------------------------
// Fallback (only if ws is too small): fused fp32 recompute per edge.
// ---------------------------------------------------------------------------
__device__ __forceinline__ void node_vals8(
    int node, int d0,
    const float* __restrict__ user_emb,
    const float* __restrict__ item_emb,
    const float* __restrict__ tag_emb,
    const float* __restrict__ testid_emb,
    const float* __restrict__ bigcat_emb,
    const float* __restrict__ daydiff_emb,
    const int* __restrict__ item_tags,
    const int* __restrict__ item_testids,
    const int* __restrict__ item_bigcat,
    const int* __restrict__ user_daydiff,
    float* v)
{
    if (node < N_USER) {
        int dd = user_daydiff[node];
        const float4* a = (const float4*)(user_emb    + (size_t)node * EMBED_DIM + d0);
        const float4* b = (const float4*)(daydiff_emb + (size_t)dd   * EMBED_DIM + d0);
        float4 a0 = a[0], a1 = a[1], b0 = b[0], b1 = b[1];
        v[0] = (a0.x + b0.x) * (0.5f * ALPHA0);
        v[1] = (a0.y + b0.y) * (0.5f * ALPHA0);
        v[2] = (a0.z + b0.z) * (0.5f * ALPHA0);
        v[3] = (a0.w + b0.w) * (0.5f * ALPHA0);
        v[4] = (a1.x + b1.x) * (0.5f * ALPHA0);
        v[5] = (a1.y + b1.y) * (0.5f * ALPHA0);
        v[6] = (a1.z + b1.z) * (0.5f * ALPHA0);
        v[7] = (a1.w + b1.w) * (0.5f * ALPHA0);
    } else {
        int i = node - N_USER;
        const float4* a = (const float4*)(item_emb   + (size_t)i * EMBED_DIM + d0);
        const float4* b = (const float4*)(tag_emb    + (size_t)item_tags[i]    * EMBED_DIM + d0);
        const float4* c = (const float4*)(testid_emb + (size_t)item_testids[i] * EMBED_DIM + d0);
        const float4* d = (const float4*)(bigcat_emb + (size_t)item_bigcat[i]  * EMBED_DIM + d0);
        float4 a0 = a[0], a1 = a[1], b0 = b[0], b1 = b[1];
        float4 c0 = c[0], c1 = c[1], d0v = d[0], d1 = d[1];
        v[0] = (a0.x + b0.x + c0.x + d0v.x) * (0.25f * ALPHA0);
        v[1] = (a0.y + b0.y + c0.y + d0v.y) * (0.25f * ALPHA0);
        v[2] = (a0.z + b0.z + c0.z + d0v.z) * (0.25f * ALPHA0);
        v[3] = (a0.w + b0.w + c0.w + d0v.w) * (0.25f * ALPHA0);
        v[4] = (a1.x + b1.x + c1.x + d1.x) * (0.25f * ALPHA0);
        v[5] = (a1.y + b1.y + c1.y + d1.y) * (0.25f * ALPHA0);
        v[6] = (a1.z + b1.z + c1.z + d1.z) * (0.25f * ALPHA0);
        v[7] = (a1.w + b1.w + c1.w + d1.w) * (0.25f * ALPHA0);
    }
}

__global__ __launch_bounds__(256) void edge_dot_fused(
    const float* __restrict__ user_emb,
    const float* __restrict__ item_emb,
    const float* __restrict__ tag_emb,
    const float* __restrict__ testid_emb,
    const float* __restrict__ bigcat_emb,
    const float* __restrict__ daydiff_emb,
    const int* __restrict__ edge_index,
    const int* __restrict__ item_tags,
    const int* __restrict__ item_testids,
    const int* __restrict__ item_bigcat,
    const int* __restrict__ user_daydiff,
    float* __restrict__ out)
{
    int tid  = blockIdx.x * 256 + threadIdx.x;
    int e    = tid >> 3;
    int g    = threadIdx.x & 7;
    int lane = threadIdx.x & 63;

    float sum = 0.0f;
    if (e < N_EDGES) {
        int src = edge_index[e];
        int dst = edge_index[N_EDGES + e];
        float a[8], b[8];
        node_vals8(src, g << 3, user_emb, item_emb, tag_emb, testid_emb,
                   bigcat_emb, daydiff_emb, item_tags, item_testids,
                   item_bigcat, user_daydiff, a);
        node_vals8(dst, g << 3, user_emb, item_emb, tag_emb, testid_emb,
                   bigcat_emb, daydiff_emb, item_tags, item_testids,
                   item_bigcat, user_daydiff, b);
        #pragma unroll
        for (int k = 0; k < 8; ++k) sum += a[k] * b[k];
    }
    sum += __shfl_xor(sum, 1, 8);
    sum += __shfl_xor(sum, 2, 8);
    sum += __shfl_xor(sum, 4, 8);

    float r = __shfl(sum, (lane & 7) << 3, 64);
    if (lane < 8) {
        int waveBase = ((blockIdx.x * 256 + (threadIdx.x & ~63)) >> 3);
        int eo = waveBase + lane;
        if (eo < N_EDGES) out[eo] = r;
    }
}

// ---------------------------------------------------------------------------
extern "C" void kernel_launch(void* const* d_in, const int* in_sizes, int n_in,
                              void* d_out, int out_size, void* d_ws, size_t ws_size,
                              hipStream_t stream)
{
    const float* user_emb    = (const float*)d_in[0];
    const float* item_emb    = (const float*)d_in[1];
    const float* tag_emb     = (const float*)d_in[2];
    const float* testid_emb  = (const float*)d_in[3];
    const float* bigcat_emb  = (const float*)d_in[4];
    const float* daydiff_emb = (const float*)d_in[5];
    const int* edge_index   = (const int*)d_in[6];
    const int* item_tags    = (const int*)d_in[7];
    const int* item_testids = (const int*)d_in[8];
    const int* item_bigcat  = (const int*)d_in[9];
    const int* user_daydiff = (const int*)d_in[10];
    float* out = (float*)d_out;

    const size_t node_bytes = (size_t)NUM_NODES * EMBED_DIM * sizeof(_Float16); // 7.68 MB

    if (ws_size >= node_bytes) {
        unsigned* nodes = (unsigned*)d_ws;
        int total = NUM_NODES * (EMBED_DIM / 4);   // uint2 elements
        build_nodes_f16<<<(total + 255) / 256, 256, 0, stream>>>(
            user_emb, item_emb, tag_emb, testid_emb, bigcat_emb, daydiff_emb,
            item_tags, item_testids, item_bigcat, user_daydiff, nodes);
        // EPG edges per 8-lane group: N_EDGES*8/EPG threads, exact division
        const int edge_blocks = (N_EDGES / EPG * 8) / 256;  // 15625
        edge_dot_f16<<<edge_blocks, 256, 0, stream>>>(nodes, edge_index, out);
    } else {
        const int edge_blocks = (N_EDGES * 8 + 255) / 256;
        edge_dot_fused<<<edge_blocks, 256, 0, stream>>>(
            user_emb, item_emb, tag_emb, testid_emb, bigcat_emb, daydiff_emb,
            edge_index, item_tags, item_testids, item_bigcat, user_daydiff, out);
    }
}